// Round 1
// baseline (12672.793 us; speedup 1.0000x reference)
//
#include <hip/hip_runtime.h>
#include <hip/hip_bf16.h>

// RecurrentAE on MI355X — round 5.
//  - 32x32x16 MFMA: 4 GEMM waves/WG on a 32-col tile -> B-operand LDS traffic cut ~3x vs
//    16x16 (768->256 KB/step), plus 24 (dec) / 16 (enc) of 64 B-frags cached in VGPRs.
//  - out GEMM moved OFF the gate WGs: 16 dedicated out-WGs (grid 144) on idle CUs, each
//    holding its W_out slice in its own LDS; out stores overlap the barrier window.
//  - Barrier: single-hop. 16 arrival counters spread 4 KB apart (distinct LLC slices);
//    EVERY WG's thread0 polls the 16 counters (no leader, no epoch round trip), then does
//    its own buffer_inv sc0 sc1. h stores remain write-through agent atomics.

#define B_ 128
#define S_ 512
#define F_ 128
#define L_ 1024
#define U_ 8
#define NWG_E 128
#define NWG_D 144          // 128 gate WGs + 16 out WGs
#define KC_D 24            // decoder B-frags cached in regs (of 64)
#define KC_E 16            // encoder (leaves room for xrg)

typedef __bf16 bf16x8 __attribute__((ext_vector_type(8)));
typedef float  f32x4  __attribute__((ext_vector_type(4)));
typedef float  f32x16 __attribute__((ext_vector_type(16)));
typedef int    i32x4  __attribute__((ext_vector_type(4)));

union pk2 { unsigned u; __bf16 h[2]; };
union fu  { float f; unsigned u; };

#define MFMA32(a, b, c) __builtin_amdgcn_mfma_f32_32x32x16_bf16(a, b, c, 0, 0, 0)
#define Z16 f32x16{0.f,0.f,0.f,0.f,0.f,0.f,0.f,0.f,0.f,0.f,0.f,0.f,0.f,0.f,0.f,0.f}

// ---------------- workspace layout (bytes) ----------------
#define O_H0   0                          // bf16 [128][1024]
#define O_H1   (256*1024)                 // bf16 [128][1024]
#define O_H32  (512*1024)                 // f32  [128][1024]
#define O_CTR  (1024*1024)                // enc ctrs 64 KB @ +0, dec ctrs 64 KB @ +65536
#define O_ZERO_END (1024*1024 + 131072)
#define O_XB   O_ZERO_END                 // bf16 [128][512][128] = 16777216
#define O_WEH  (O_XB  + 16777216)         // bf16 [128][32][1024] = 8388608
#define O_WEX  (O_WEH + 8388608)          // bf16 [128][32][128]  = 1048576
#define O_BE   (O_WEX + 1048576)          // f32  [128][32]       = 16384
#define O_WD   (O_BE  + 16384)            // bf16 [128][32][1024] = 8388608
#define O_BD   (O_WD  + 8388608)          // f32  [128][32]       = 16384
#define O_WC   (O_BD  + 16384)            // bf16 [3072][1024]    = 6291456
#define O_WOB  (O_WC  + 6291456)          // bf16 [128][1024]     = 262144
// total ~41.3 MB

// ---------------- prep kernels ----------------

__global__ void k_xcvt(const float* __restrict__ x, __bf16* __restrict__ xb, int n) {
    int i = blockIdx.x * 256 + threadIdx.x;
    int stride = gridDim.x * 256;
    for (; i < n; i += stride) xb[i] = (__bf16)x[i];
}

__global__ void k_woutb(const float* __restrict__ Wout, __bf16* __restrict__ Wob, int n) {
    int i = blockIdx.x * 256 + threadIdx.x;
    if (i < n) Wob[i] = (__bf16)Wout[i];
}

// encoder pack: 32 cols/WG, 4 per unit {r, z, n_i, n_h}
__global__ void k_pack_enc(const float* __restrict__ Wih, const float* __restrict__ Whh,
                           const float* __restrict__ bih, const float* __restrict__ bhh,
                           __bf16* __restrict__ Weh, __bf16* __restrict__ Wex,
                           float* __restrict__ be) {
    int g = blockIdx.x, tid = threadIdx.x;
    for (int i = tid; i < 32 * 1024; i += 256) {
        int c = i >> 10, k = i & 1023;
        int u = g * U_ + (c >> 2), gate = c & 3;
        float v = 0.f;
        if (gate == 0)      v = Whh[(size_t)u * 1024 + k];
        else if (gate == 1) v = Whh[(size_t)(1024 + u) * 1024 + k];
        else if (gate == 3) v = Whh[(size_t)(2048 + u) * 1024 + k];
        Weh[((size_t)g * 32 + c) * 1024 + k] = (__bf16)v;
    }
    for (int i = tid; i < 32 * 128; i += 256) {
        int c = i >> 7, k = i & 127;
        int u = g * U_ + (c >> 2), gate = c & 3;
        float v = 0.f;
        if (gate == 0)      v = Wih[(size_t)u * 128 + k];
        else if (gate == 1) v = Wih[(size_t)(1024 + u) * 128 + k];
        else if (gate == 2) v = Wih[(size_t)(2048 + u) * 128 + k];
        Wex[((size_t)g * 32 + c) * 128 + k] = (__bf16)v;
    }
    if (tid < 32) {
        int c = tid, u = g * U_ + (c >> 2), gate = c & 3;
        float v;
        if (gate == 0)      v = bih[u] + bhh[u];
        else if (gate == 1) v = bih[1024 + u] + bhh[1024 + u];
        else if (gate == 2) v = bih[2048 + u];
        else                v = bhh[2048 + u];
        be[g * 32 + c] = v;
    }
}

// W_comb = W_ih_d @ W_out
__global__ void k_wcomb(const float* __restrict__ Wihd, const float* __restrict__ Wout,
                        __bf16* __restrict__ Wc) {
    __shared__ float a[8][128];
    int r0 = blockIdx.x * 8, tid = threadIdx.x;
    for (int i = tid; i < 8 * 128; i += 256)
        a[i >> 7][i & 127] = Wihd[(size_t)(r0 + (i >> 7)) * 128 + (i & 127)];
    __syncthreads();
    for (int j = tid; j < 1024; j += 256) {
        float acc[8] = {0, 0, 0, 0, 0, 0, 0, 0};
        for (int f = 0; f < 128; ++f) {
            float w = Wout[(size_t)f * 1024 + j];
#pragma unroll
            for (int r = 0; r < 8; ++r) acc[r] += a[r][f] * w;
        }
        for (int r = 0; r < 8; ++r) Wc[(size_t)(r0 + r) * 1024 + j] = (__bf16)acc[r];
    }
}

// decoder pack: 32 cols/WG {r:Whh+Wc, z:Whh+Wc, n_i:Wc, n_h:Whh}
__global__ void k_pack_dec(const float* __restrict__ Whhd, const __bf16* __restrict__ Wc,
                           const float* __restrict__ Wihd,
                           const float* __restrict__ bihd, const float* __restrict__ bhhd,
                           const float* __restrict__ bout,
                           __bf16* __restrict__ Wd, float* __restrict__ bd) {
    int g = blockIdx.x, tid = threadIdx.x;
    for (int i = tid; i < 32 * 1024; i += 256) {
        int c = i >> 10, k = i & 1023;
        int u = g * U_ + (c >> 2), gate = c & 3;
        float v;
        if (gate == 0)      v = Whhd[(size_t)u * 1024 + k] + (float)Wc[(size_t)u * 1024 + k];
        else if (gate == 1) v = Whhd[(size_t)(1024 + u) * 1024 + k] + (float)Wc[(size_t)(1024 + u) * 1024 + k];
        else if (gate == 2) v = (float)Wc[(size_t)(2048 + u) * 1024 + k];
        else                v = Whhd[(size_t)(2048 + u) * 1024 + k];
        Wd[((size_t)g * 32 + c) * 1024 + k] = (__bf16)v;
    }
    if (tid < 32) {
        int c = tid;
        int u = g * U_ + (c >> 2), gate = c & 3;
        int row = (gate == 0) ? u : (gate == 1) ? (1024 + u) : (2048 + u);
        float v;
        if (gate <= 1) {
            float d = 0.f;
            for (int f = 0; f < 128; ++f) d += Wihd[(size_t)row * 128 + f] * bout[f];
            v = d + bihd[row] + bhhd[row];
        } else if (gate == 2) {
            float d = 0.f;
            for (int f = 0; f < 128; ++f) d += Wihd[(size_t)row * 128 + f] * bout[f];
            v = d + bihd[row];
        } else {
            v = bhhd[row];
        }
        bd[g * 32 + c] = v;
    }
}

// ---------------- barrier: 16 counters @ 4 KB stride, single-hop all-poll ----------------

__device__ __forceinline__ void bar_arrive(unsigned* base, int g) {
    if (threadIdx.x == 0)
        __hip_atomic_fetch_add(base + (g & 15) * 1024, 1u,
                               __ATOMIC_RELAXED, __HIP_MEMORY_SCOPE_AGENT);
}

__device__ __forceinline__ void bar_wait(unsigned* base, unsigned tgt) {
    if (threadIdx.x == 0) {
        for (;;) {
            unsigned sum = 0;
#pragma unroll
            for (int j = 0; j < 16; ++j)
                sum += __hip_atomic_load(base + j * 1024, __ATOMIC_RELAXED, __HIP_MEMORY_SCOPE_AGENT);
            if (sum >= tgt) break;
            __builtin_amdgcn_s_sleep(1);
        }
        // own L1+L2 invalidate; h producers wrote through, so refill from LLC is fresh.
        asm volatile("buffer_inv sc0 sc1\n\ts_waitcnt vmcnt(0)" ::: "memory");
    }
    __syncthreads();
}

// ---------------- encoder ----------------
__global__ __launch_bounds__(512) void k_enc(
    const __bf16* __restrict__ xb, const __bf16* __restrict__ Weh,
    const __bf16* __restrict__ Wex, const float* __restrict__ be,
    __bf16* __restrict__ h0, __bf16* __restrict__ h1,
    float* __restrict__ h32, unsigned* __restrict__ ctr) {
    __shared__ __align__(16) __bf16 sWh[32][1032];
    __shared__ __align__(16) __bf16 sWx[32][136];
    __shared__ float sB[32];
    __shared__ __align__(16) float sG[128][36];
    const int g = blockIdx.x, tid = threadIdx.x;
    const int lane = tid & 63, wave = tid >> 6;

    for (int i = tid; i < 32 * 128; i += 512) {
        int c = i >> 7, k8 = i & 127;
        *(i32x4*)&sWh[c][k8 * 8] = *(const i32x4*)(Weh + ((size_t)g * 32 + c) * 1024 + k8 * 8);
    }
    for (int i = tid; i < 32 * 16; i += 512) {
        int c = i >> 4, k8 = i & 15;
        *(i32x4*)&sWx[c][k8 * 8] = *(const i32x4*)(Wex + ((size_t)g * 32 + c) * 128 + k8 * 8);
    }
    if (tid < 32) sB[tid] = be[g * 32 + tid];
    __syncthreads();

    const int bcol = lane & 31;
    const int koff = (lane >> 5) * 8;            // halves
    const int mrow = (wave & 3) * 32 + bcol;     // A row (batch) for GEMM waves
    const bool gw = (wave < 4);

    bf16x8 brg[KC_E];
    bf16x8 xrg[8];
    if (gw) {
#pragma unroll
        for (int kt = 0; kt < KC_E; ++kt) brg[kt] = *(const bf16x8*)(&sWh[bcol][kt * 16 + koff]);
#pragma unroll
        for (int kt = 0; kt < 8; ++kt)    xrg[kt] = *(const bf16x8*)(&sWx[bcol][kt * 16 + koff]);
    }

    const int erow = tid >> 2, pair = tid & 3;
    const int hidx2 = erow * 512 + g * 4 + pair;
    float ha = 0.f, hb = 0.f;

    // x-part of step 0
    f32x16 accx = Z16;
    if (gw) {
        const __bf16* xr = xb + (size_t)mrow * 65536;
#pragma unroll
        for (int kt = 0; kt < 8; ++kt)
            accx = MFMA32(*(const bf16x8*)(xr + kt * 16 + koff), xrg[kt], accx);
    }

    for (int s = 0; s < 512; ++s) {
        const __bf16* hcur = (s & 1) ? h1 : h0;
        __bf16* hnxt = (s & 1) ? h0 : h1;
        if (gw) {
            f32x16 aA = accx, aB = Z16;       // dual chains for MFMA pipelining
            const __bf16* hr = hcur + (size_t)mrow * 1024;
#pragma unroll
            for (int kt = 0; kt < KC_E; kt += 2) {
                aA = MFMA32(*(const bf16x8*)(hr + kt * 16 + koff),       brg[kt],     aA);
                aB = MFMA32(*(const bf16x8*)(hr + (kt + 1) * 16 + koff), brg[kt + 1], aB);
            }
#pragma unroll
            for (int kt = KC_E; kt < 64; kt += 2) {
                aA = MFMA32(*(const bf16x8*)(hr + kt * 16 + koff),
                            *(const bf16x8*)(&sWh[bcol][kt * 16 + koff]), aA);
                aB = MFMA32(*(const bf16x8*)(hr + (kt + 1) * 16 + koff),
                            *(const bf16x8*)(&sWh[bcol][(kt + 1) * 16 + koff]), aB);
            }
            f32x16 acc = aA + aB;
            // C frag: col = lane&31, row = (r&3) + 8*(r>>2) + 4*(lane>>5)
            int rb = (wave & 3) * 32 + 4 * (lane >> 5);
#pragma unroll
            for (int r = 0; r < 16; ++r)
                sG[rb + (r & 3) + 8 * (r >> 2)][bcol] = acc[r];
        }
        __syncthreads();
        {
            f32x4 g0 = *(const f32x4*)&sG[erow][pair * 8];
            f32x4 g1 = *(const f32x4*)&sG[erow][pair * 8 + 4];
            int c0 = pair * 8;
            float r = 1.f / (1.f + __expf(-(g0[0] + sB[c0 + 0])));
            float z = 1.f / (1.f + __expf(-(g0[1] + sB[c0 + 1])));
            float n = tanhf(g0[2] + sB[c0 + 2] + r * (g0[3] + sB[c0 + 3]));
            ha = (1.f - z) * n + z * ha;
            r = 1.f / (1.f + __expf(-(g1[0] + sB[c0 + 4])));
            z = 1.f / (1.f + __expf(-(g1[1] + sB[c0 + 5])));
            n = tanhf(g1[2] + sB[c0 + 6] + r * (g1[3] + sB[c0 + 7]));
            hb = (1.f - z) * n + z * hb;
            pk2 p; p.h[0] = (__bf16)ha; p.h[1] = (__bf16)hb;
            __hip_atomic_store((unsigned*)hnxt + hidx2, p.u, __ATOMIC_RELAXED, __HIP_MEMORY_SCOPE_AGENT);
            if (s == 511) {
                h32[erow * 1024 + g * 8 + pair * 2]     = ha;
                h32[erow * 1024 + g * 8 + pair * 2 + 1] = hb;
            }
        }
        if (s < 511) {
            __syncthreads();              // drains write-through h stores
            bar_arrive(ctr, g);
            // overlap: x-part of step s+1 (x read-only -> safe pre-inv)
            if (gw) {
                f32x16 ax = Z16;
                const __bf16* xr = xb + (size_t)mrow * 65536 + (size_t)(s + 1) * 128;
#pragma unroll
                for (int kt = 0; kt < 8; ++kt)
                    ax = MFMA32(*(const bf16x8*)(xr + kt * 16 + koff), xrg[kt], ax);
                accx = ax;
            }
            bar_wait(ctr, (unsigned)(s + 1) * NWG_E);
        }
    }
}

// ---------------- decoder ----------------
// g < 128  : gate WG (32 gate cols, waves 0-3 GEMM, all waves gate math)
// g >= 128 : out WG  (one 32x32 out tile; wave 0 GEMM + stores, overlapped with barrier)
__global__ __launch_bounds__(512) void k_dec(
    const __bf16* __restrict__ Wd, const float* __restrict__ bd,
    const __bf16* __restrict__ Wob, const float* __restrict__ bout,
    __bf16* __restrict__ h0, __bf16* __restrict__ h1,
    const float* __restrict__ h32, float* __restrict__ out,
    unsigned* __restrict__ ctr) {
    __shared__ __align__(16) __bf16 sW[32][1032];
    __shared__ float sB[32];
    __shared__ __align__(16) float sG[128][36];
    const int g = blockIdx.x, tid = threadIdx.x;
    const int lane = tid & 63, wave = tid >> 6;
    const bool gwg = (g < 128);
    const int go = g - 128;

    if (gwg) {
        for (int i = tid; i < 32 * 128; i += 512) {
            int c = i >> 7, k8 = i & 127;
            *(i32x4*)&sW[c][k8 * 8] = *(const i32x4*)(Wd + ((size_t)g * 32 + c) * 1024 + k8 * 8);
        }
        if (tid < 32) sB[tid] = bd[g * 32 + tid];
    } else {
        for (int i = tid; i < 32 * 128; i += 512) {
            int c = i >> 7, k8 = i & 127;
            *(i32x4*)&sW[c][k8 * 8] =
                *(const i32x4*)(Wob + ((size_t)((go >> 2) * 32 + c)) * 1024 + k8 * 8);
        }
    }
    __syncthreads();

    const int bcol = lane & 31;
    const int koff = (lane >> 5) * 8;
    const bool gw = gwg ? (wave < 4) : (wave == 0);
    const int arow = gwg ? ((wave & 3) * 32 + bcol)   // batch row, gate gemm
                         : ((go & 3) * 32 + bcol);    // batch row, out gemm

    bf16x8 brg[KC_D];
    if (gw) {
#pragma unroll
        for (int kt = 0; kt < KC_D; ++kt) brg[kt] = *(const bf16x8*)(&sW[bcol][kt * 16 + koff]);
    }

    const int erow = tid >> 2, pair = tid & 3;
    const int hidx2 = erow * 512 + g * 4 + pair;
    float ha = 0.f, hb = 0.f;
    if (gwg) {
        ha = h32[erow * 1024 + g * 8 + pair * 2];
        hb = h32[erow * 1024 + g * 8 + pair * 2 + 1];
    }
    float obias = 0.f; int fcol = 0;
    if (!gwg) { fcol = (go >> 2) * 32 + bcol; obias = bout[fcol]; }

    if (gwg) {
        for (int s = 0; s < 512; ++s) {
            const __bf16* hcur = (s & 1) ? h1 : h0;
            __bf16* hnxt = (s & 1) ? h0 : h1;
            if (gw) {
                f32x16 aA = Z16, aB = Z16;
                const __bf16* hr = hcur + (size_t)arow * 1024;
#pragma unroll
                for (int kt = 0; kt < KC_D; kt += 2) {
                    aA = MFMA32(*(const bf16x8*)(hr + kt * 16 + koff),       brg[kt],     aA);
                    aB = MFMA32(*(const bf16x8*)(hr + (kt + 1) * 16 + koff), brg[kt + 1], aB);
                }
#pragma unroll
                for (int kt = KC_D; kt < 64; kt += 2) {
                    aA = MFMA32(*(const bf16x8*)(hr + kt * 16 + koff),
                                *(const bf16x8*)(&sW[bcol][kt * 16 + koff]), aA);
                    aB = MFMA32(*(const bf16x8*)(hr + (kt + 1) * 16 + koff),
                                *(const bf16x8*)(&sW[bcol][(kt + 1) * 16 + koff]), aB);
                }
                f32x16 acc = aA + aB;
                int rb = (wave & 3) * 32 + 4 * (lane >> 5);
#pragma unroll
                for (int r = 0; r < 16; ++r)
                    sG[rb + (r & 3) + 8 * (r >> 2)][bcol] = acc[r];
            }
            __syncthreads();
            {
                f32x4 g0 = *(const f32x4*)&sG[erow][pair * 8];
                f32x4 g1 = *(const f32x4*)&sG[erow][pair * 8 + 4];
                int c0 = pair * 8;
                float r = 1.f / (1.f + __expf(-(g0[0] + sB[c0 + 0])));
                float z = 1.f / (1.f + __expf(-(g0[1] + sB[c0 + 1])));
                float n = tanhf(g0[2] + sB[c0 + 2] + r * (g0[3] + sB[c0 + 3]));
                ha = (1.f - z) * n + z * ha;
                r = 1.f / (1.f + __expf(-(g1[0] + sB[c0 + 4])));
                z = 1.f / (1.f + __expf(-(g1[1] + sB[c0 + 5])));
                n = tanhf(g1[2] + sB[c0 + 6] + r * (g1[3] + sB[c0 + 7]));
                hb = (1.f - z) * n + z * hb;
                pk2 p; p.h[0] = (__bf16)ha; p.h[1] = (__bf16)hb;
                __hip_atomic_store((unsigned*)hnxt + hidx2, p.u, __ATOMIC_RELAXED, __HIP_MEMORY_SCOPE_AGENT);
            }
            __syncthreads();              // drains write-through h stores
            bar_arrive(ctr, g);
            if (s < 511) bar_wait(ctr, (unsigned)(s + 1) * NWG_D);
        }
    } else {
        // out WG: iteration s computes out_{s-1} = h_s @ W_out^T + b (s = 1..512)
        for (int s = 0; s <= 512; ++s) {
            const __bf16* hcur = (s & 1) ? h1 : h0;
            const bool cmp = (wave == 0) && (s >= 1);
            f32x16 acc = Z16;
            if (cmp) {
                f32x16 aA = Z16, aB = Z16;
                const __bf16* hr = hcur + (size_t)arow * 1024;
#pragma unroll
                for (int kt = 0; kt < KC_D; kt += 2) {
                    aA = MFMA32(*(const bf16x8*)(hr + kt * 16 + koff),       brg[kt],     aA);
                    aB = MFMA32(*(const bf16x8*)(hr + (kt + 1) * 16 + koff), brg[kt + 1], aB);
                }
#pragma unroll
                for (int kt = KC_D; kt < 64; kt += 2) {
                    aA = MFMA32(*(const bf16x8*)(hr + kt * 16 + koff),
                                *(const bf16x8*)(&sW[bcol][kt * 16 + koff]), aA);
                    aB = MFMA32(*(const bf16x8*)(hr + (kt + 1) * 16 + koff),
                                *(const bf16x8*)(&sW[bcol][(kt + 1) * 16 + koff]), aB);
                }
                acc = aA + aB;
            }
            if (s < 512) bar_arrive(ctr, g);   // h reads already consumed into acc
            if (cmp) {
                // write-through stores, overlapped with the poll; coalesced along f
                int rb = 4 * (lane >> 5);
#pragma unroll
                for (int r = 0; r < 16; ++r) {
                    int b = (go & 3) * 32 + rb + (r & 3) + 8 * (r >> 2);
                    fu cv; cv.f = acc[r] + obias;
                    __hip_atomic_store((unsigned*)(out + ((size_t)b * 512 + (size_t)(512 - s)) * 128 + fcol),
                                       cv.u, __ATOMIC_RELAXED, __HIP_MEMORY_SCOPE_AGENT);
                }
            }
            if (s < 512) bar_wait(ctr, (unsigned)(s + 1) * NWG_D);
        }
    }
}

// ---------------- launch ----------------
extern "C" void kernel_launch(void* const* d_in, const int* in_sizes, int n_in,
                              void* d_out, int out_size, void* d_ws, size_t ws_size,
                              hipStream_t stream) {
    (void)in_sizes; (void)n_in; (void)out_size; (void)ws_size;
    const float* x    = (const float*)d_in[0];
    const float* Wihe = (const float*)d_in[1];
    const float* Whhe = (const float*)d_in[2];
    const float* bihe = (const float*)d_in[3];
    const float* bhhe = (const float*)d_in[4];
    const float* Wihd = (const float*)d_in[5];
    const float* Whhd = (const float*)d_in[6];
    const float* bihd = (const float*)d_in[7];
    const float* bhhd = (const float*)d_in[8];
    const float* Wout = (const float*)d_in[9];
    const float* bout = (const float*)d_in[10];

    char* ws = (char*)d_ws;
    __bf16*   h0  = (__bf16*)(ws + O_H0);
    __bf16*   h1  = (__bf16*)(ws + O_H1);
    float*    h32 = (float*)(ws + O_H32);
    unsigned* ctr = (unsigned*)(ws + O_CTR);
    __bf16*   xbf = (__bf16*)(ws + O_XB);
    __bf16*   Weh = (__bf16*)(ws + O_WEH);
    __bf16*   Wex = (__bf16*)(ws + O_WEX);
    float*    be  = (float*)(ws + O_BE);
    __bf16*   Wd  = (__bf16*)(ws + O_WD);
    float*    bd  = (float*)(ws + O_BD);
    __bf16*   Wc  = (__bf16*)(ws + O_WC);
    __bf16*   Wob = (__bf16*)(ws + O_WOB);

    hipMemsetAsync(ws, 0, O_ZERO_END, stream);   // h0/h1/h32 + both counter blocks

    k_xcvt<<<4096, 256, 0, stream>>>(x, xbf, B_ * S_ * F_);
    k_pack_enc<<<NWG_E, 256, 0, stream>>>(Wihe, Whhe, bihe, bhhe, Weh, Wex, be);
    k_wcomb<<<384, 256, 0, stream>>>(Wihd, Wout, Wc);
    k_pack_dec<<<NWG_E, 256, 0, stream>>>(Whhd, Wc, Wihd, bihd, bhhd, bout, Wd, bd);
    k_woutb<<<512, 256, 0, stream>>>(Wout, Wob, F_ * L_);

    k_enc<<<NWG_E, 512, 0, stream>>>(xbf, Weh, Wex, be, h0, h1, h32, ctr);
    k_dec<<<NWG_D, 512, 0, stream>>>(Wd, bd, Wob, bout, h0, h1, h32, (float*)d_out,
                                     ctr + 16384);
}

// Round 3
// 10160.114 us; speedup vs baseline: 1.2473x; 1.2473x over previous
//
#include <hip/hip_runtime.h>
#include <hip/hip_bf16.h>

// RecurrentAE on MI355X — round 7 (= round 6 + deadlock fix).
//  - Round-6 deadlock: gate-WG leaders exited at s=511 without publishing epoch 512;
//    out-WGs spun forever in their final bar_wait. FIX: gate WGs run bar_wait for ALL s
//    (incl. s=511 -> leader publishes epoch 512, releasing out-WGs' last iteration).
//  - Barrier: round-4 leader scheme (1 L2-inv per XCD per step, epoch broadcast).
//  - 32x32x16 MFMA, K-split GEMM across 8 waves (32 K-frags/wave, partials in sGa/sGb),
//    16-deep rolling A-prefetch for 2x memory-level parallelism on the h reload.
//  - 16 dedicated out-WGs (grid 144) overlap out GEMM + stores with the barrier window.

#define B_ 128
#define S_ 512
#define F_ 128
#define L_ 1024
#define U_ 8
#define NWG_E 128
#define NWG_D 144          // 128 gate WGs + 16 out WGs

typedef __bf16 bf16x8 __attribute__((ext_vector_type(8)));
typedef float  f32x4  __attribute__((ext_vector_type(4)));
typedef float  f32x16 __attribute__((ext_vector_type(16)));
typedef int    i32x4  __attribute__((ext_vector_type(4)));

union pk2 { unsigned u; __bf16 h[2]; };
union fu  { float f; unsigned u; };

#define MFMA32(a, b, c) __builtin_amdgcn_mfma_f32_32x32x16_bf16(a, b, c, 0, 0, 0)
#define Z16 f32x16{0.f,0.f,0.f,0.f,0.f,0.f,0.f,0.f,0.f,0.f,0.f,0.f,0.f,0.f,0.f,0.f}

// ---------------- workspace layout (bytes) ----------------
#define O_H0   0                          // bf16 [128][1024]
#define O_H1   (256*1024)                 // bf16 [128][1024]
#define O_H32  (512*1024)                 // f32  [128][1024]
#define O_CTR  (1024*1024)                // sync: enc @ +0, dec @ +4096 (1024 u32 each)
#define O_ZERO_END (1024*1024 + 8192)
#define O_XB   O_ZERO_END                 // bf16 [128][512][128] = 16777216
#define O_WEH  (O_XB  + 16777216)         // bf16 [128][32][1024] = 8388608
#define O_WEX  (O_WEH + 8388608)          // bf16 [128][32][128]  = 1048576
#define O_BE   (O_WEX + 1048576)          // f32  [128][32]       = 16384
#define O_WD   (O_BE  + 16384)            // bf16 [128][32][1024] = 8388608
#define O_BD   (O_WD  + 8388608)          // f32  [128][32]       = 16384
#define O_WC   (O_BD  + 16384)            // bf16 [3072][1024]    = 6291456
#define O_WOB  (O_WC  + 6291456)          // bf16 [128][1024]     = 262144
// total ~42 MB

// ---------------- prep kernels ----------------

__global__ void k_xcvt(const float* __restrict__ x, __bf16* __restrict__ xb, int n) {
    int i = blockIdx.x * 256 + threadIdx.x;
    int stride = gridDim.x * 256;
    for (; i < n; i += stride) xb[i] = (__bf16)x[i];
}

__global__ void k_woutb(const float* __restrict__ Wout, __bf16* __restrict__ Wob, int n) {
    int i = blockIdx.x * 256 + threadIdx.x;
    if (i < n) Wob[i] = (__bf16)Wout[i];
}

// encoder pack: 32 cols/WG, 4 per unit {r, z, n_i, n_h}
__global__ void k_pack_enc(const float* __restrict__ Wih, const float* __restrict__ Whh,
                           const float* __restrict__ bih, const float* __restrict__ bhh,
                           __bf16* __restrict__ Weh, __bf16* __restrict__ Wex,
                           float* __restrict__ be) {
    int g = blockIdx.x, tid = threadIdx.x;
    for (int i = tid; i < 32 * 1024; i += 256) {
        int c = i >> 10, k = i & 1023;
        int u = g * U_ + (c >> 2), gate = c & 3;
        float v = 0.f;
        if (gate == 0)      v = Whh[(size_t)u * 1024 + k];
        else if (gate == 1) v = Whh[(size_t)(1024 + u) * 1024 + k];
        else if (gate == 3) v = Whh[(size_t)(2048 + u) * 1024 + k];
        Weh[((size_t)g * 32 + c) * 1024 + k] = (__bf16)v;
    }
    for (int i = tid; i < 32 * 128; i += 256) {
        int c = i >> 7, k = i & 127;
        int u = g * U_ + (c >> 2), gate = c & 3;
        float v = 0.f;
        if (gate == 0)      v = Wih[(size_t)u * 128 + k];
        else if (gate == 1) v = Wih[(size_t)(1024 + u) * 128 + k];
        else if (gate == 2) v = Wih[(size_t)(2048 + u) * 128 + k];
        Wex[((size_t)g * 32 + c) * 128 + k] = (__bf16)v;
    }
    if (tid < 32) {
        int c = tid, u = g * U_ + (c >> 2), gate = c & 3;
        float v;
        if (gate == 0)      v = bih[u] + bhh[u];
        else if (gate == 1) v = bih[1024 + u] + bhh[1024 + u];
        else if (gate == 2) v = bih[2048 + u];
        else                v = bhh[2048 + u];
        be[g * 32 + c] = v;
    }
}

// W_comb = W_ih_d @ W_out
__global__ void k_wcomb(const float* __restrict__ Wihd, const float* __restrict__ Wout,
                        __bf16* __restrict__ Wc) {
    __shared__ float a[8][128];
    int r0 = blockIdx.x * 8, tid = threadIdx.x;
    for (int i = tid; i < 8 * 128; i += 256)
        a[i >> 7][i & 127] = Wihd[(size_t)(r0 + (i >> 7)) * 128 + (i & 127)];
    __syncthreads();
    for (int j = tid; j < 1024; j += 256) {
        float acc[8] = {0, 0, 0, 0, 0, 0, 0, 0};
        for (int f = 0; f < 128; ++f) {
            float w = Wout[(size_t)f * 1024 + j];
#pragma unroll
            for (int r = 0; r < 8; ++r) acc[r] += a[r][f] * w;
        }
        for (int r = 0; r < 8; ++r) Wc[(size_t)(r0 + r) * 1024 + j] = (__bf16)acc[r];
    }
}

// decoder pack: 32 cols/WG {r:Whh+Wc, z:Whh+Wc, n_i:Wc, n_h:Whh}
__global__ void k_pack_dec(const float* __restrict__ Whhd, const __bf16* __restrict__ Wc,
                           const float* __restrict__ Wihd,
                           const float* __restrict__ bihd, const float* __restrict__ bhhd,
                           const float* __restrict__ bout,
                           __bf16* __restrict__ Wd, float* __restrict__ bd) {
    int g = blockIdx.x, tid = threadIdx.x;
    for (int i = tid; i < 32 * 1024; i += 256) {
        int c = i >> 10, k = i & 1023;
        int u = g * U_ + (c >> 2), gate = c & 3;
        float v;
        if (gate == 0)      v = Whhd[(size_t)u * 1024 + k] + (float)Wc[(size_t)u * 1024 + k];
        else if (gate == 1) v = Whhd[(size_t)(1024 + u) * 1024 + k] + (float)Wc[(size_t)(1024 + u) * 1024 + k];
        else if (gate == 2) v = (float)Wc[(size_t)(2048 + u) * 1024 + k];
        else                v = Whhd[(size_t)(2048 + u) * 1024 + k];
        Wd[((size_t)g * 32 + c) * 1024 + k] = (__bf16)v;
    }
    if (tid < 32) {
        int c = tid;
        int u = g * U_ + (c >> 2), gate = c & 3;
        int row = (gate == 0) ? u : (gate == 1) ? (1024 + u) : (2048 + u);
        float v;
        if (gate <= 1) {
            float d = 0.f;
            for (int f = 0; f < 128; ++f) d += Wihd[(size_t)row * 128 + f] * bout[f];
            v = d + bihd[row] + bhhd[row];
        } else if (gate == 2) {
            float d = 0.f;
            for (int f = 0; f < 128; ++f) d += Wihd[(size_t)row * 128 + f] * bout[f];
            v = d + bihd[row];
        } else {
            v = bhhd[row];
        }
        bd[g * 32 + c] = v;
    }
}

// ---------------- sync block (round-4 leader scheme) ----------------
//   subs : [j*32]        j<16   (arrival counters, 128B apart)
//   epoch: [512 + x*32]  x<8    (per-XCD step epoch, written by leader)
//   claim: [768 + x*32]  x<8    (leader election)

__device__ __forceinline__ void bar_arrive(unsigned* base, int g) {
    if (threadIdx.x == 0)
        __hip_atomic_fetch_add(base + (g & 15) * 32, 1u,
                               __ATOMIC_RELAXED, __HIP_MEMORY_SCOPE_AGENT);
}

__device__ __forceinline__ void bar_wait(unsigned* base, int xcd, bool lead,
                                         unsigned step1, unsigned nwg) {
    if (threadIdx.x == 0) {
        if (lead) {
            unsigned tgt = step1 * nwg;
            for (;;) {
                unsigned sum = 0;
#pragma unroll
                for (int j = 0; j < 16; ++j)
                    sum += __hip_atomic_load(base + j * 32, __ATOMIC_RELAXED, __HIP_MEMORY_SCOPE_AGENT);
                if (sum >= tgt) break;
                __builtin_amdgcn_s_sleep(1);
            }
            // ONE L2(+L1) invalidate per XCD per step, before releasing this XCD's WGs.
            asm volatile("buffer_inv sc0 sc1\n\ts_waitcnt vmcnt(0)" ::: "memory");
            __hip_atomic_store(base + 512 + xcd * 32, step1,
                               __ATOMIC_RELAXED, __HIP_MEMORY_SCOPE_AGENT);
        } else {
            while (__hip_atomic_load(base + 512 + xcd * 32,
                                     __ATOMIC_RELAXED, __HIP_MEMORY_SCOPE_AGENT) < step1)
                __builtin_amdgcn_s_sleep(1);
            // own-CU L1 invalidate only
            asm volatile("buffer_inv sc0\n\ts_waitcnt vmcnt(0)" ::: "memory");
        }
    }
    __syncthreads();
}

__device__ __forceinline__ void elect(unsigned* base, int& xcd, bool& lead) {
    if (threadIdx.x == 0) {
        int x;
        asm volatile("s_getreg_b32 %0, hwreg(HW_REG_XCC_ID)" : "=s"(x));
        xcd = x & 7;
        unsigned old = __hip_atomic_fetch_add(base + 768 + xcd * 32, 1u,
                                              __ATOMIC_RELAXED, __HIP_MEMORY_SCOPE_AGENT);
        lead = (old == 0);
    }
}

// ---------------- encoder ----------------
// 8 GEMM waves: wave w (w<4) rows (w&3)*32, K-frags 0..31 -> sGa;
//               wave w+4     same rows,     K-frags 32..63 -> sGb (+ x part, overlapped).
__global__ __launch_bounds__(512, 2) void k_enc(
    const __bf16* __restrict__ xb, const __bf16* __restrict__ Weh,
    const __bf16* __restrict__ Wex, const float* __restrict__ be,
    __bf16* __restrict__ h0, __bf16* __restrict__ h1,
    float* __restrict__ h32, unsigned* __restrict__ ctr) {
    __shared__ __align__(16) __bf16 sWh[32][1032];
    __shared__ __align__(16) __bf16 sWx[32][136];
    __shared__ float sB[32];
    __shared__ __align__(16) float sGa[128][36];
    __shared__ __align__(16) float sGb[128][36];
    const int g = blockIdx.x, tid = threadIdx.x;
    const int lane = tid & 63, wave = tid >> 6;

    int xcd = 0; bool lead = false;
    elect(ctr, xcd, lead);

    for (int i = tid; i < 32 * 128; i += 512) {
        int c = i >> 7, k8 = i & 127;
        *(i32x4*)&sWh[c][k8 * 8] = *(const i32x4*)(Weh + ((size_t)g * 32 + c) * 1024 + k8 * 8);
    }
    for (int i = tid; i < 32 * 16; i += 512) {
        int c = i >> 4, k8 = i & 15;
        *(i32x4*)&sWx[c][k8 * 8] = *(const i32x4*)(Wex + ((size_t)g * 32 + c) * 128 + k8 * 8);
    }
    if (tid < 32) sB[tid] = be[g * 32 + tid];
    __syncthreads();

    const int bcol = lane & 31;
    const int koff = (lane >> 5) * 8;
    const int mrow = (wave & 3) * 32 + bcol;
    const int kb = (wave >> 2) * 32;           // this wave's K-frag base
    const bool up = (wave >= 4);

    bf16x8 xrg[8];
    if (up) {
#pragma unroll
        for (int kt = 0; kt < 8; ++kt) xrg[kt] = *(const bf16x8*)(&sWx[bcol][kt * 16 + koff]);
    }

    const int erow = tid >> 2, pair = tid & 3;
    const int hidx2 = erow * 512 + g * 4 + pair;
    float ha = 0.f, hb = 0.f;

    // x-part of step 0 (upper waves)
    f32x16 accx = Z16;
    if (up) {
        const __bf16* xr = xb + (size_t)mrow * 65536;
#pragma unroll
        for (int kt = 0; kt < 8; ++kt)
            accx = MFMA32(*(const bf16x8*)(xr + kt * 16 + koff), xrg[kt], accx);
    }

    for (int s = 0; s < 512; ++s) {
        const __bf16* hcur = (s & 1) ? h1 : h0;
        __bf16* hnxt = (s & 1) ? h0 : h1;
        {
            f32x16 aA = up ? accx : Z16;
            f32x16 aB = Z16;
            const __bf16* hr = hcur + (size_t)mrow * 1024 + kb * 16;
            bf16x8 af[16];
#pragma unroll
            for (int i = 0; i < 16; ++i) af[i] = *(const bf16x8*)(hr + i * 16 + koff);
#pragma unroll
            for (int i = 0; i < 16; ++i) {
                bf16x8 a = af[i];
                af[i] = *(const bf16x8*)(hr + (16 + i) * 16 + koff);
                const bf16x8 b = *(const bf16x8*)(&sWh[bcol][(kb + i) * 16 + koff]);
                if (i & 1) aB = MFMA32(a, b, aB); else aA = MFMA32(a, b, aA);
            }
#pragma unroll
            for (int i = 0; i < 16; ++i) {
                const bf16x8 b = *(const bf16x8*)(&sWh[bcol][(kb + 16 + i) * 16 + koff]);
                if (i & 1) aB = MFMA32(af[i], b, aB); else aA = MFMA32(af[i], b, aA);
            }
            f32x16 acc = aA + aB;
            // C frag: col = lane&31, row = (r&3) + 8*(r>>2) + 4*(lane>>5)
            int rb = (wave & 3) * 32 + 4 * (lane >> 5);
            float (*sg)[36] = up ? sGb : sGa;
#pragma unroll
            for (int r = 0; r < 16; ++r)
                sg[rb + (r & 3) + 8 * (r >> 2)][bcol] = acc[r];
        }
        __syncthreads();
        {
            f32x4 g0 = *(const f32x4*)&sGa[erow][pair * 8] + *(const f32x4*)&sGb[erow][pair * 8];
            f32x4 g1 = *(const f32x4*)&sGa[erow][pair * 8 + 4] + *(const f32x4*)&sGb[erow][pair * 8 + 4];
            int c0 = pair * 8;
            float r = 1.f / (1.f + __expf(-(g0[0] + sB[c0 + 0])));
            float z = 1.f / (1.f + __expf(-(g0[1] + sB[c0 + 1])));
            float n = tanhf(g0[2] + sB[c0 + 2] + r * (g0[3] + sB[c0 + 3]));
            ha = (1.f - z) * n + z * ha;
            r = 1.f / (1.f + __expf(-(g1[0] + sB[c0 + 4])));
            z = 1.f / (1.f + __expf(-(g1[1] + sB[c0 + 5])));
            n = tanhf(g1[2] + sB[c0 + 6] + r * (g1[3] + sB[c0 + 7]));
            hb = (1.f - z) * n + z * hb;
            pk2 p; p.h[0] = (__bf16)ha; p.h[1] = (__bf16)hb;
            __hip_atomic_store((unsigned*)hnxt + hidx2, p.u, __ATOMIC_RELAXED, __HIP_MEMORY_SCOPE_AGENT);
            if (s == 511) {
                h32[erow * 1024 + g * 8 + pair * 2]     = ha;
                h32[erow * 1024 + g * 8 + pair * 2 + 1] = hb;
            }
        }
        if (s < 511) {
            __syncthreads();              // drains write-through h stores
            bar_arrive(ctr, g);
            // overlap: x-part of step s+1 (x read-only -> safe pre-inv)
            if (up) {
                f32x16 ax = Z16;
                const __bf16* xr = xb + (size_t)mrow * 65536 + (size_t)(s + 1) * 128;
#pragma unroll
                for (int kt = 0; kt < 8; ++kt)
                    ax = MFMA32(*(const bf16x8*)(xr + kt * 16 + koff), xrg[kt], ax);
                accx = ax;
            }
            bar_wait(ctr, xcd, lead, (unsigned)(s + 1), NWG_E);
        }
    }
}

// ---------------- decoder ----------------
// g < 128  : gate WG (32 gate cols; 8 K-split GEMM waves; all waves gate math)
// g >= 128 : out WG  (one 32x32 out tile; wave 0 GEMM + stores, overlapped with barrier)
__global__ __launch_bounds__(512, 2) void k_dec(
    const __bf16* __restrict__ Wd, const float* __restrict__ bd,
    const __bf16* __restrict__ Wob, const float* __restrict__ bout,
    __bf16* __restrict__ h0, __bf16* __restrict__ h1,
    const float* __restrict__ h32, float* __restrict__ out,
    unsigned* __restrict__ ctr) {
    __shared__ __align__(16) __bf16 sW[32][1032];
    __shared__ float sB[32];
    __shared__ __align__(16) float sGa[128][36];
    __shared__ __align__(16) float sGb[128][36];
    const int g = blockIdx.x, tid = threadIdx.x;
    const int lane = tid & 63, wave = tid >> 6;
    const bool gwg = (g < 128);
    const int go = g - 128;

    int xcd = 0; bool lead = false;
    elect(ctr, xcd, lead);

    if (gwg) {
        for (int i = tid; i < 32 * 128; i += 512) {
            int c = i >> 7, k8 = i & 127;
            *(i32x4*)&sW[c][k8 * 8] = *(const i32x4*)(Wd + ((size_t)g * 32 + c) * 1024 + k8 * 8);
        }
        if (tid < 32) sB[tid] = bd[g * 32 + tid];
    } else {
        for (int i = tid; i < 32 * 128; i += 512) {
            int c = i >> 7, k8 = i & 127;
            *(i32x4*)&sW[c][k8 * 8] =
                *(const i32x4*)(Wob + ((size_t)((go >> 2) * 32 + c)) * 1024 + k8 * 8);
        }
    }
    __syncthreads();

    const int bcol = lane & 31;
    const int koff = (lane >> 5) * 8;
    const int kb = (wave >> 2) * 32;
    const bool up = (wave >= 4);
    const int arow = gwg ? ((wave & 3) * 32 + bcol)   // batch row, gate gemm
                         : ((go & 3) * 32 + bcol);    // batch row, out gemm

    const int erow = tid >> 2, pair = tid & 3;
    const int hidx2 = erow * 512 + g * 4 + pair;
    float ha = 0.f, hb = 0.f;
    if (gwg) {
        ha = h32[erow * 1024 + g * 8 + pair * 2];
        hb = h32[erow * 1024 + g * 8 + pair * 2 + 1];
    }
    float obias = 0.f; int fcol = 0;
    if (!gwg) { fcol = (go >> 2) * 32 + bcol; obias = bout[fcol]; }

    if (gwg) {
        for (int s = 0; s < 512; ++s) {
            const __bf16* hcur = (s & 1) ? h1 : h0;
            __bf16* hnxt = (s & 1) ? h0 : h1;
            {
                f32x16 aA = Z16, aB = Z16;
                const __bf16* hr = hcur + (size_t)arow * 1024 + kb * 16;
                bf16x8 af[16];
#pragma unroll
                for (int i = 0; i < 16; ++i) af[i] = *(const bf16x8*)(hr + i * 16 + koff);
#pragma unroll
                for (int i = 0; i < 16; ++i) {
                    bf16x8 a = af[i];
                    af[i] = *(const bf16x8*)(hr + (16 + i) * 16 + koff);
                    const bf16x8 b = *(const bf16x8*)(&sW[bcol][(kb + i) * 16 + koff]);
                    if (i & 1) aB = MFMA32(a, b, aB); else aA = MFMA32(a, b, aA);
                }
#pragma unroll
                for (int i = 0; i < 16; ++i) {
                    const bf16x8 b = *(const bf16x8*)(&sW[bcol][(kb + 16 + i) * 16 + koff]);
                    if (i & 1) aB = MFMA32(af[i], b, aB); else aA = MFMA32(af[i], b, aA);
                }
                f32x16 acc = aA + aB;
                int rb = (wave & 3) * 32 + 4 * (lane >> 5);
                float (*sg)[36] = up ? sGb : sGa;
#pragma unroll
                for (int r = 0; r < 16; ++r)
                    sg[rb + (r & 3) + 8 * (r >> 2)][bcol] = acc[r];
            }
            __syncthreads();
            {
                f32x4 g0 = *(const f32x4*)&sGa[erow][pair * 8] + *(const f32x4*)&sGb[erow][pair * 8];
                f32x4 g1 = *(const f32x4*)&sGa[erow][pair * 8 + 4] + *(const f32x4*)&sGb[erow][pair * 8 + 4];
                int c0 = pair * 8;
                float r = 1.f / (1.f + __expf(-(g0[0] + sB[c0 + 0])));
                float z = 1.f / (1.f + __expf(-(g0[1] + sB[c0 + 1])));
                float n = tanhf(g0[2] + sB[c0 + 2] + r * (g0[3] + sB[c0 + 3]));
                ha = (1.f - z) * n + z * ha;
                r = 1.f / (1.f + __expf(-(g1[0] + sB[c0 + 4])));
                z = 1.f / (1.f + __expf(-(g1[1] + sB[c0 + 5])));
                n = tanhf(g1[2] + sB[c0 + 6] + r * (g1[3] + sB[c0 + 7]));
                hb = (1.f - z) * n + z * hb;
                pk2 p; p.h[0] = (__bf16)ha; p.h[1] = (__bf16)hb;
                __hip_atomic_store((unsigned*)hnxt + hidx2, p.u, __ATOMIC_RELAXED, __HIP_MEMORY_SCOPE_AGENT);
            }
            __syncthreads();              // drains write-through h stores
            bar_arrive(ctr, g);
            // UNCONDITIONAL: at s=511 the leader must publish epoch 512 so the
            // 16 out-WGs can run their final (s=512) iteration. (Round-6 deadlock fix.)
            bar_wait(ctr, xcd, lead, (unsigned)(s + 1), NWG_D);
        }
    } else {
        // out WG: iteration s computes out col 512-s = h_s @ W_out^T + b (s = 1..512)
        for (int s = 0; s <= 512; ++s) {
            const __bf16* hcur = (s & 1) ? h1 : h0;
            const bool cmp = (wave == 0) && (s >= 1);
            f32x16 acc = Z16;
            if (cmp) {
                f32x16 aA = Z16, aB = Z16;
                const __bf16* hr = hcur + (size_t)arow * 1024;
                bf16x8 af[16];
#pragma unroll
                for (int i = 0; i < 16; ++i) af[i] = *(const bf16x8*)(hr + i * 16 + koff);
#pragma unroll
                for (int kt = 0; kt < 48; ++kt) {
                    bf16x8 a = af[kt & 15];
                    af[kt & 15] = *(const bf16x8*)(hr + (kt + 16) * 16 + koff);
                    const bf16x8 b = *(const bf16x8*)(&sW[bcol][kt * 16 + koff]);
                    if (kt & 1) aB = MFMA32(a, b, aB); else aA = MFMA32(a, b, aA);
                }
#pragma unroll
                for (int kt = 48; kt < 64; ++kt) {
                    const bf16x8 b = *(const bf16x8*)(&sW[bcol][kt * 16 + koff]);
                    if (kt & 1) aB = MFMA32(af[kt & 15], b, aB); else aA = MFMA32(af[kt & 15], b, aA);
                }
                acc = aA + aB;
            }
            if (s < 512) bar_arrive(ctr, g);   // h reads already consumed into acc
            if (cmp) {
                // write-through stores, overlapped with the barrier window
                int rb = 4 * (lane >> 5);
#pragma unroll
                for (int r = 0; r < 16; ++r) {
                    int b = (go & 3) * 32 + rb + (r & 3) + 8 * (r >> 2);
                    fu cv; cv.f = acc[r] + obias;
                    __hip_atomic_store((unsigned*)(out + ((size_t)b * 512 + (size_t)(512 - s)) * 128 + fcol),
                                       cv.u, __ATOMIC_RELAXED, __HIP_MEMORY_SCOPE_AGENT);
                }
            }
            if (s < 512) bar_wait(ctr, xcd, lead, (unsigned)(s + 1), NWG_D);
        }
    }
}

// ---------------- launch ----------------
extern "C" void kernel_launch(void* const* d_in, const int* in_sizes, int n_in,
                              void* d_out, int out_size, void* d_ws, size_t ws_size,
                              hipStream_t stream) {
    (void)in_sizes; (void)n_in; (void)out_size; (void)ws_size;
    const float* x    = (const float*)d_in[0];
    const float* Wihe = (const float*)d_in[1];
    const float* Whhe = (const float*)d_in[2];
    const float* bihe = (const float*)d_in[3];
    const float* bhhe = (const float*)d_in[4];
    const float* Wihd = (const float*)d_in[5];
    const float* Whhd = (const float*)d_in[6];
    const float* bihd = (const float*)d_in[7];
    const float* bhhd = (const float*)d_in[8];
    const float* Wout = (const float*)d_in[9];
    const float* bout = (const float*)d_in[10];

    char* ws = (char*)d_ws;
    __bf16*   h0  = (__bf16*)(ws + O_H0);
    __bf16*   h1  = (__bf16*)(ws + O_H1);
    float*    h32 = (float*)(ws + O_H32);
    unsigned* ctr = (unsigned*)(ws + O_CTR);
    __bf16*   xbf = (__bf16*)(ws + O_XB);
    __bf16*   Weh = (__bf16*)(ws + O_WEH);
    __bf16*   Wex = (__bf16*)(ws + O_WEX);
    float*    be  = (float*)(ws + O_BE);
    __bf16*   Wd  = (__bf16*)(ws + O_WD);
    float*    bd  = (float*)(ws + O_BD);
    __bf16*   Wc  = (__bf16*)(ws + O_WC);
    __bf16*   Wob = (__bf16*)(ws + O_WOB);

    hipMemsetAsync(ws, 0, O_ZERO_END, stream);   // h0/h1/h32 + both sync blocks

    k_xcvt<<<4096, 256, 0, stream>>>(x, xbf, B_ * S_ * F_);
    k_pack_enc<<<NWG_E, 256, 0, stream>>>(Wihe, Whhe, bihe, bhhe, Weh, Wex, be);
    k_wcomb<<<384, 256, 0, stream>>>(Wihd, Wout, Wc);
    k_pack_dec<<<NWG_E, 256, 0, stream>>>(Whhd, Wc, Wihd, bihd, bhhd, bout, Wd, bd);
    k_woutb<<<512, 256, 0, stream>>>(Wout, Wob, F_ * L_);

    k_enc<<<NWG_E, 512, 0, stream>>>(xbf, Weh, Wex, be, h0, h1, h32, ctr);
    k_dec<<<NWG_D, 512, 0, stream>>>(Wd, bd, Wob, bout, h0, h1, h32, (float*)d_out,
                                     ctr + 1024);
}